// Round 6
// baseline (1151.313 us; speedup 1.0000x reference)
//
#include <hip/hip_runtime.h>
#include <math.h>

#define NFEAT 128
#define NHID  24
#define NCLS  16
#define H1STR 32                // h1s bf16 row stride (64 B line-aligned)
#define NBSH  7                 // 128 nodes per bucket
#define BKN   128
#define TILE  8192              // edges per partition tile
#define PT    1024              // partition block threads

typedef unsigned short ushort_t;

__device__ __forceinline__ float bf2f(ushort_t u) {
    unsigned x = ((unsigned)u) << 16;
    float f;
    __builtin_memcpy(&f, &x, 4);
    return f;
}
__device__ __forceinline__ ushort_t f2bf(float f) {
    unsigned x;
    __builtin_memcpy(&x, &f, 4);
    unsigned r = (x + 0x7FFF + ((x >> 16) & 1)) >> 16;   // RNE
    return (ushort_t)r;
}
__device__ __forceinline__ float lo_f(unsigned u) {   // bf16 pair -> float of low half
    unsigned x = u << 16;
    float f; __builtin_memcpy(&f, &x, 4); return f;
}
__device__ __forceinline__ float hi_f(unsigned u) {   // float of high half (free mask)
    unsigned x = u & 0xFFFF0000u;
    float f; __builtin_memcpy(&f, &x, 4); return f;
}

// ---------------------------------------------------------------------------
// K1: bucket histogram (LDS) + per-node degree (global atomics, 400 KB table)
__global__ void __launch_bounds__(512) bhist_deg_kernel(const int* __restrict__ ei,
                                                        int* __restrict__ bhist,
                                                        int* __restrict__ deg,
                                                        int E) {
    __shared__ int lh[1024];
    lh[threadIdx.x] = 0;
    lh[threadIdx.x + 512] = 0;
    __syncthreads();
    int stride = gridDim.x * blockDim.x;
    for (int e = blockIdx.x * blockDim.x + threadIdx.x; e < E; e += stride) {
        int d = ei[e];
        atomicAdd(&lh[d >> NBSH], 1);
        atomicAdd(&deg[d], 1);
    }
    __syncthreads();
    if (lh[threadIdx.x]) atomicAdd(&bhist[threadIdx.x], lh[threadIdx.x]);
    if (lh[threadIdx.x + 512]) atomicAdd(&bhist[threadIdx.x + 512], lh[threadIdx.x + 512]);
}

// K2: exclusive scan of bucket counts -> bbase (sentinel), gcur
__global__ void __launch_bounds__(1024) bscan_kernel(const int* __restrict__ bhist,
                                                     int* __restrict__ bbase,
                                                     int* __restrict__ gcur,
                                                     int NBUCK, int E) {
    __shared__ int s[1024];
    int t = threadIdx.x;
    int v = (t < NBUCK) ? bhist[t] : 0;
    s[t] = v;
    __syncthreads();
    for (int o = 1; o < 1024; o <<= 1) {
        int x = (t >= o) ? s[t - o] : 0;
        __syncthreads();
        s[t] += x;
        __syncthreads();
    }
    if (t < NBUCK) {
        int ex = s[t] - v;
        bbase[t] = ex;
        gcur[t] = ex;
    }
    if (t == 0) bbase[NBUCK] = E;
}

// K3: dinv = rsqrt(deg + 1)
__global__ void __launch_bounds__(512) dinv_kernel(const int* __restrict__ deg,
                                                   float* __restrict__ dinv, int N) {
    int i = blockIdx.x * blockDim.x + threadIdx.x;
    if (i < N) dinv[i] = rsqrtf((float)deg[i] + 1.0f);
}

// K4: LDS-staged partition; entry = (local_dst<<17) | src  (local<128, src<2^17)
__global__ void __launch_bounds__(1024) part1_kernel(const int* __restrict__ ei,
                                                     int* __restrict__ gcur,
                                                     int* __restrict__ part,
                                                     int E, int NBUCK) {
    __shared__ int stage[TILE];   // 32 KB
    __shared__ int lh[1024];      // hist -> cursor
    __shared__ int sc[1024];
    __shared__ int lofs[1024];
    __shared__ int gbase[1024];
    int t = threadIdx.x;
    int e0 = blockIdx.x * TILE;
    int cnt_tile = min(TILE, E - e0);
    lh[t] = 0;
    __syncthreads();
    for (int i = t; i < cnt_tile; i += PT)
        atomicAdd(&lh[ei[e0 + i] >> NBSH], 1);
    __syncthreads();
    sc[t] = lh[t];
    __syncthreads();
    for (int o = 1; o < 1024; o <<= 1) {
        int v = (t >= o) ? sc[t - o] : 0;
        __syncthreads();
        sc[t] += v;
        __syncthreads();
    }
    {
        int cb = lh[t];
        int ex = sc[t] - cb;
        lofs[t] = (t < NBUCK) ? ex : cnt_tile;
        gbase[t] = (cb && t < NBUCK) ? atomicAdd(&gcur[t], cb) : 0;
        lh[t] = ex;   // LDS cursor
    }
    __syncthreads();
    for (int i = t; i < cnt_tile; i += PT) {
        int dst = ei[e0 + i];
        int src = ei[E + e0 + i];
        int b = dst >> NBSH;
        int p = atomicAdd(&lh[b], 1);
        stage[p] = ((dst & (BKN - 1)) << 17) | src;
    }
    __syncthreads();
    for (int i = t; i < cnt_tile; i += PT) {   // coalesced copy-out
        int lo = 0, hi = 1023;
        while (lo < hi) {
            int mid = (lo + hi + 1) >> 1;
            if (lofs[mid] <= i) lo = mid; else hi = mid - 1;
        }
        part[gbase[lo] + (i - lofs[lo])] = stage[i];
    }
}

// K5: h1s(bf16, stride 32) = dinv[row] * (x @ W1); W1 in LDS
__global__ void __launch_bounds__(256) gemm1_kernel(const float* __restrict__ x,
                                                    const float* __restrict__ W1,
                                                    const float* __restrict__ dinv,
                                                    unsigned* __restrict__ h1u, int N) {
    __shared__ float w[NFEAT * NHID];
    for (int i = threadIdx.x; i < NFEAT * NHID; i += blockDim.x) w[i] = W1[i];
    __syncthreads();
    int row = blockIdx.x * blockDim.x + threadIdx.x;
    if (row >= N) return;
    float acc[NHID];
#pragma unroll
    for (int j = 0; j < NHID; j++) acc[j] = 0.0f;
    const float4* xr = (const float4*)(x + (size_t)row * NFEAT);
    for (int k4 = 0; k4 < NFEAT / 4; k4++) {
        float4 v = xr[k4];
        const float* wr = &w[k4 * 4 * NHID];
#pragma unroll
        for (int j = 0; j < NHID; j++) acc[j] += v.x * wr[j];
#pragma unroll
        for (int j = 0; j < NHID; j++) acc[j] += v.y * wr[NHID + j];
#pragma unroll
        for (int j = 0; j < NHID; j++) acc[j] += v.z * wr[2 * NHID + j];
#pragma unroll
        for (int j = 0; j < NHID; j++) acc[j] += v.w * wr[3 * NHID + j];
    }
    float di = dinv[row];
    unsigned* o = h1u + (size_t)row * (H1STR / 2);
#pragma unroll
    for (int q = 0; q < NHID / 2; q++)
        o[q] = (unsigned)f2bf(di * acc[2 * q]) | ((unsigned)f2bf(di * acc[2 * q + 1]) << 16);
}

// K6: layer-1 bucket aggregation: one block per 128-node bucket, LDS fp32 acc.
//     512 thr = 42 edge-slots x 12 lanes (ushort2 per lane); 4-way unroll.
//     Epilogue: hrelu = relu(dinv*(acc + self) + b1)
__global__ void __launch_bounds__(512) agg1_kernel(const int* __restrict__ part,
                                                   const int* __restrict__ bbase,
                                                   const unsigned* __restrict__ h1u,
                                                   const ushort_t* __restrict__ h1sb,
                                                   const float* __restrict__ dinv,
                                                   const float* __restrict__ b1,
                                                   float* __restrict__ hrelu, int N) {
    __shared__ float acc[BKN * NHID];   // 12 KB
    int b = blockIdx.x, t = threadIdx.x;
    for (int i = t; i < BKN * NHID; i += 512) acc[i] = 0.0f;
    __syncthreads();
    int st = bbase[b], en = bbase[b + 1];
    int slot = t / 12;                  // 0..42 (42 partial -> idle)
    int lane = t - slot * 12;           // 0..11
    int f = 2 * lane;
    int e = (slot < 42) ? st + slot : en;
    for (; e + 126 < en; e += 168) {    // 4-way unroll, stride 42
        int e0 = part[e], e1 = part[e + 42], e2 = part[e + 84], e3 = part[e + 126];
        unsigned u0 = h1u[(e0 & 0x1FFFF) * (H1STR / 2) + lane];
        unsigned u1 = h1u[(e1 & 0x1FFFF) * (H1STR / 2) + lane];
        unsigned u2 = h1u[(e2 & 0x1FFFF) * (H1STR / 2) + lane];
        unsigned u3 = h1u[(e3 & 0x1FFFF) * (H1STR / 2) + lane];
        atomicAdd(&acc[(e0 >> 17) * NHID + f], lo_f(u0));
        atomicAdd(&acc[(e0 >> 17) * NHID + f + 1], hi_f(u0));
        atomicAdd(&acc[(e1 >> 17) * NHID + f], lo_f(u1));
        atomicAdd(&acc[(e1 >> 17) * NHID + f + 1], hi_f(u1));
        atomicAdd(&acc[(e2 >> 17) * NHID + f], lo_f(u2));
        atomicAdd(&acc[(e2 >> 17) * NHID + f + 1], hi_f(u2));
        atomicAdd(&acc[(e3 >> 17) * NHID + f], lo_f(u3));
        atomicAdd(&acc[(e3 >> 17) * NHID + f + 1], hi_f(u3));
    }
    for (; e < en; e += 42) {
        int ent = part[e];
        unsigned u = h1u[(ent & 0x1FFFF) * (H1STR / 2) + lane];
        atomicAdd(&acc[(ent >> 17) * NHID + f], lo_f(u));
        atomicAdd(&acc[(ent >> 17) * NHID + f + 1], hi_f(u));
    }
    __syncthreads();
    for (int i = t; i < BKN * NHID; i += 512) {
        int ln = i / NHID;
        int ff = i - ln * NHID;
        int node = (b << NBSH) + ln;
        if (node < N) {
            float v = dinv[node] * (acc[i] + bf2f(h1sb[node * H1STR + ff])) + b1[ff];
            hrelu[node * NHID + ff] = fmaxf(v, 0.0f);
        }
    }
}

// K7: h2s(bf16, stride 16) = dinv[row] * (hrelu @ W2)
__global__ void __launch_bounds__(256) fuse2_kernel(const float* __restrict__ hrelu,
                                                    const float* __restrict__ dinv,
                                                    const float* __restrict__ W2,
                                                    unsigned* __restrict__ h2u, int N) {
    __shared__ float w[NHID * NCLS];
    for (int i = threadIdx.x; i < NHID * NCLS; i += blockDim.x) w[i] = W2[i];
    __syncthreads();
    int row = blockIdx.x * blockDim.x + threadIdx.x;
    if (row >= N) return;
    float hr[NHID];
    const float4* h4 = (const float4*)(hrelu + (size_t)row * NHID);
#pragma unroll
    for (int q = 0; q < NHID / 4; q++) {
        float4 hv = h4[q];
        hr[4 * q + 0] = hv.x;
        hr[4 * q + 1] = hv.y;
        hr[4 * q + 2] = hv.z;
        hr[4 * q + 3] = hv.w;
    }
    float acc[NCLS];
#pragma unroll
    for (int j = 0; j < NCLS; j++) acc[j] = 0.0f;
#pragma unroll
    for (int k = 0; k < NHID; k++) {
#pragma unroll
        for (int j = 0; j < NCLS; j++) acc[j] += hr[k] * w[k * NCLS + j];
    }
    float di = dinv[row];
    unsigned* o = h2u + (size_t)row * (NCLS / 2);
#pragma unroll
    for (int q = 0; q < NCLS / 2; q++)
        o[q] = (unsigned)f2bf(di * acc[2 * q]) | ((unsigned)f2bf(di * acc[2 * q + 1]) << 16);
}

// K8: layer-2 bucket aggregation + self-loop + b2 + log_softmax.
//     512 thr = 64 edge-slots x 8 lanes (ushort2); LDS acc 128x16 fp32.
__global__ void __launch_bounds__(512) agg2_kernel(const int* __restrict__ part,
                                                   const int* __restrict__ bbase,
                                                   const unsigned* __restrict__ h2u,
                                                   const ushort_t* __restrict__ h2sb,
                                                   const float* __restrict__ dinv,
                                                   const float* __restrict__ b2,
                                                   float* __restrict__ out, int N) {
    __shared__ float acc[BKN * NCLS];   // 8 KB
    int b = blockIdx.x, t = threadIdx.x;
    for (int i = t; i < BKN * NCLS; i += 512) acc[i] = 0.0f;
    __syncthreads();
    int st = bbase[b], en = bbase[b + 1];
    int slot = t >> 3;                  // 0..63
    int lane = t & 7;
    int f = 2 * lane;
    int e = st + slot;
    for (; e + 192 < en; e += 256) {    // 4-way unroll, stride 64
        int e0 = part[e], e1 = part[e + 64], e2 = part[e + 128], e3 = part[e + 192];
        unsigned u0 = h2u[(e0 & 0x1FFFF) * (NCLS / 2) + lane];
        unsigned u1 = h2u[(e1 & 0x1FFFF) * (NCLS / 2) + lane];
        unsigned u2 = h2u[(e2 & 0x1FFFF) * (NCLS / 2) + lane];
        unsigned u3 = h2u[(e3 & 0x1FFFF) * (NCLS / 2) + lane];
        atomicAdd(&acc[(e0 >> 17) * NCLS + f], lo_f(u0));
        atomicAdd(&acc[(e0 >> 17) * NCLS + f + 1], hi_f(u0));
        atomicAdd(&acc[(e1 >> 17) * NCLS + f], lo_f(u1));
        atomicAdd(&acc[(e1 >> 17) * NCLS + f + 1], hi_f(u1));
        atomicAdd(&acc[(e2 >> 17) * NCLS + f], lo_f(u2));
        atomicAdd(&acc[(e2 >> 17) * NCLS + f + 1], hi_f(u2));
        atomicAdd(&acc[(e3 >> 17) * NCLS + f], lo_f(u3));
        atomicAdd(&acc[(e3 >> 17) * NCLS + f + 1], hi_f(u3));
    }
    for (; e < en; e += 64) {
        int ent = part[e];
        unsigned u = h2u[(ent & 0x1FFFF) * (NCLS / 2) + lane];
        atomicAdd(&acc[(ent >> 17) * NCLS + f], lo_f(u));
        atomicAdd(&acc[(ent >> 17) * NCLS + f + 1], hi_f(u));
    }
    __syncthreads();
    int ff = t & 15;
    for (int r = 0; r < 4; r++) {       // 32 nodes per round
        int ln = r * 32 + (t >> 4);
        int node = (b << NBSH) + ln;
        if (node < N) {
            float l = dinv[node] * (acc[ln * NCLS + ff] + bf2f(h2sb[node * NCLS + ff])) + b2[ff];
            float m = l;
#pragma unroll
            for (int o = 1; o < 16; o <<= 1) m = fmaxf(m, __shfl_xor(m, o, 16));
            float ex = expf(l - m);
            float ssum = ex;
#pragma unroll
            for (int o = 1; o < 16; o <<= 1) ssum += __shfl_xor(ssum, o, 16);
            out[node * NCLS + ff] = l - (logf(ssum) + m);
        }
    }
}

extern "C" void kernel_launch(void* const* d_in, const int* in_sizes, int n_in,
                              void* d_out, int out_size, void* d_ws, size_t ws_size,
                              hipStream_t stream) {
    const float* x  = (const float*)d_in[0];
    const int*   ei = (const int*)d_in[1];
    const float* W1 = (const float*)d_in[2];
    const float* b1 = (const float*)d_in[3];
    const float* W2 = (const float*)d_in[4];
    const float* b2 = (const float*)d_in[5];
    float* out = (float*)d_out;

    const int N = in_sizes[0] / NFEAT;        // 100000
    const int E = in_sizes[1] / 2;            // 3200000
    const int NBUCK = (N + BKN - 1) >> NBSH;  // 782

    // workspace: [deg N][bhist 1024][bbase 1025][gcur 1024] ints, [dinv N] f32,
    // 64B-aligned: [h1sb N*32 bf16][hrelu N*24 f32][part E ints]
    int* deg   = (int*)d_ws;
    int* bhist = deg + N;
    int* bbase = bhist + 1024;
    int* gcur  = bbase + 1025;
    float* dinv = (float*)(gcur + 1024);
    size_t off = (size_t)(N + 1024 + 1025 + 1024 + N) * 4;
    off = (off + 63) & ~(size_t)63;
    ushort_t* h1sb = (ushort_t*)((char*)d_ws + off);           // 6.4 MB
    ushort_t* h2sb = h1sb;                                     // alias, h1s dead after agg1
    size_t off2 = off + (size_t)N * H1STR * 2;
    off2 = (off2 + 63) & ~(size_t)63;
    float* hrelu = (float*)((char*)d_ws + off2);               // 9.6 MB
    size_t off3 = off2 + (size_t)N * NHID * 4;
    off3 = (off3 + 63) & ~(size_t)63;
    int* part = (int*)((char*)d_ws + off3);                    // 12.8 MB

    // zero deg + bhist in one contiguous memset
    hipMemsetAsync(deg, 0, ((size_t)N + 1024) * sizeof(int), stream);

    bhist_deg_kernel<<<512, 512, 0, stream>>>(ei, bhist, deg, E);
    bscan_kernel<<<1, 1024, 0, stream>>>(bhist, bbase, gcur, NBUCK, E);
    dinv_kernel<<<(N + 511) / 512, 512, 0, stream>>>(deg, dinv, N);
    part1_kernel<<<(E + TILE - 1) / TILE, PT, 0, stream>>>(ei, gcur, part, E, NBUCK);
    gemm1_kernel<<<(N + 255) / 256, 256, 0, stream>>>(x, W1, dinv, (unsigned*)h1sb, N);
    agg1_kernel<<<NBUCK, 512, 0, stream>>>(part, bbase, (const unsigned*)h1sb, h1sb,
                                           dinv, b1, hrelu, N);
    fuse2_kernel<<<(N + 255) / 256, 256, 0, stream>>>(hrelu, dinv, W2, (unsigned*)h2sb, N);
    agg2_kernel<<<NBUCK, 512, 0, stream>>>(part, bbase, (const unsigned*)h2sb, h2sb,
                                           dinv, b2, out, N);
}

// Round 7
// 392.903 us; speedup vs baseline: 2.9303x; 2.9303x over previous
//
#include <hip/hip_runtime.h>
#include <math.h>

#define NFEAT 128
#define NHID  24
#define NCLS  16
#define H1STR 32                // h1s bf16 row stride (64 B line-aligned)
#define NBSH  8                 // 256 nodes per bucket
#define BKN   256
#define QSH   15                // src-quarter shift (sub-sort key for L2 phasing)
#define TILE  8192              // edges per partition tile
#define PT    512               // partition block threads

typedef unsigned short ushort_t;

__device__ __forceinline__ float bf2f(ushort_t u) {
    unsigned x = ((unsigned)u) << 16;
    float f; __builtin_memcpy(&f, &x, 4); return f;
}
__device__ __forceinline__ ushort_t f2bf(float f) {
    unsigned x; __builtin_memcpy(&x, &f, 4);
    unsigned r = (x + 0x7FFF + ((x >> 16) & 1)) >> 16;   // RNE
    return (ushort_t)r;
}
__device__ __forceinline__ float lo_f(unsigned u) {   // low bf16 of pair -> float
    unsigned x = u << 16;
    float f; __builtin_memcpy(&f, &x, 4); return f;
}
__device__ __forceinline__ float hi_f(unsigned u) {   // high bf16 of pair -> float
    unsigned x = u & 0xFFFF0000u;
    float f; __builtin_memcpy(&f, &x, 4); return f;
}

// ---------------------------------------------------------------------------
// K1: per-node degree, plain global atomics (400 KB table, ~32 adds/counter)
__global__ void __launch_bounds__(512) deg_kernel(const int* __restrict__ ei,
                                                  int* __restrict__ deg, int E) {
    int e = blockIdx.x * blockDim.x + threadIdx.x;
    if (e < E) atomicAdd(&deg[ei[e]], 1);
}

// K2: dinv = rsqrt(deg + 1)
__global__ void __launch_bounds__(512) dinv_kernel(const int* __restrict__ deg,
                                                   float* __restrict__ dinv, int N) {
    int i = blockIdx.x * blockDim.x + threadIdx.x;
    if (i < N) dinv[i] = rsqrtf((float)deg[i] + 1.0f);
}

// K3: bucket counts = segment-sum of deg over 256-node buckets
__global__ void __launch_bounds__(256) bucketsum_kernel(const int* __restrict__ deg,
                                                        int* __restrict__ bcnt, int N) {
    __shared__ int s[256];
    int b = blockIdx.x, t = threadIdx.x;
    int node = (b << NBSH) + t;
    s[t] = (node < N) ? deg[node] : 0;
    __syncthreads();
    for (int o = 128; o > 0; o >>= 1) {
        if (t < o) s[t] += s[t + o];
        __syncthreads();
    }
    if (t == 0) bcnt[b] = s[0];
}

// K4: exclusive scan of bucket counts -> bbase (sentinel), gcur
__global__ void __launch_bounds__(512) bscan_kernel(const int* __restrict__ bcnt,
                                                    int* __restrict__ bbase,
                                                    int* __restrict__ gcur,
                                                    int NBUCK, int E) {
    __shared__ int s[512];
    int t = threadIdx.x;
    int v = (t < NBUCK) ? bcnt[t] : 0;
    s[t] = v;
    __syncthreads();
    for (int o = 1; o < 512; o <<= 1) {
        int x = (t >= o) ? s[t - o] : 0;
        __syncthreads();
        s[t] += x;
        __syncthreads();
    }
    if (t < NBUCK) {
        int ex = s[t] - v;
        bbase[t] = ex;
        gcur[t] = ex;
    }
    if (t == 0) bbase[NBUCK] = E;
}

// K5: LDS-staged partition into 256-node buckets; entry = (local_dst<<17) | src
__global__ void __launch_bounds__(512) part1_kernel(const int* __restrict__ ei,
                                                    int* __restrict__ gcur,
                                                    int* __restrict__ part, int E) {
    __shared__ int stage[TILE];   // 32 KB
    __shared__ int lh[512];       // hist -> cursor
    __shared__ int sc[512];
    __shared__ int lofs[513];
    __shared__ int gbase[512];
    int t = threadIdx.x;
    int e0 = blockIdx.x * TILE;
    int cnt_tile = min(TILE, E - e0);
    lh[t] = 0;
    __syncthreads();
    for (int i = t; i < cnt_tile; i += PT)
        atomicAdd(&lh[ei[e0 + i] >> NBSH], 1);
    __syncthreads();
    sc[t] = lh[t];
    __syncthreads();
    for (int o = 1; o < 512; o <<= 1) {
        int v = (t >= o) ? sc[t - o] : 0;
        __syncthreads();
        sc[t] += v;
        __syncthreads();
    }
    {
        int cb = lh[t];
        int ex = sc[t] - cb;
        lofs[t] = ex;
        gbase[t] = cb ? atomicAdd(&gcur[t], cb) : 0;
        lh[t] = ex;   // LDS cursor
    }
    if (t == 0) lofs[512] = cnt_tile;
    __syncthreads();
    for (int i = t; i < cnt_tile; i += PT) {
        int dst = ei[e0 + i];
        int src = ei[E + e0 + i];
        int b = dst >> NBSH;
        int p = atomicAdd(&lh[b], 1);
        stage[p] = ((dst & (BKN - 1)) << 17) | src;
    }
    __syncthreads();
    for (int i = t; i < cnt_tile; i += PT) {   // coalesced copy-out
        int lo = 0, hi = 511;
        while (lo < hi) {
            int mid = (lo + hi + 1) >> 1;
            if (lofs[mid] <= i) lo = mid; else hi = mid - 1;
        }
        part[gbase[lo] + (i - lofs[lo])] = stage[i];
    }
}

// K6: per-bucket CSR build, key = local_dst*4 + src_quarter (1024 keys).
//     The src-quarter sub-sort makes agg gathers walk ~2.1 MB L2-resident slices.
__global__ void __launch_bounds__(1024) csr_kernel(const int* __restrict__ part,
                                                   const int* __restrict__ bbase,
                                                   int* __restrict__ csr,
                                                   int* __restrict__ rowst,
                                                   int NBUCK, int N, int E) {
    __shared__ int h[1024];
    __shared__ int cur[1024];
    int b = blockIdx.x, t = threadIdx.x;
    int st = bbase[b], en = bbase[b + 1];
    h[t] = 0;
    __syncthreads();
    for (int e = st + t; e < en; e += 1024) {
        int ent = part[e];
        atomicAdd(&h[((ent >> 17) << 2) | ((ent & 0x1FFFF) >> QSH)], 1);
    }
    __syncthreads();
    int myc = h[t];
    for (int o = 1; o < 1024; o <<= 1) {   // inclusive scan
        int v = (t >= o) ? h[t - o] : 0;
        __syncthreads();
        h[t] += v;
        __syncthreads();
    }
    int ex = h[t] - myc;
    if ((t & 3) == 0) {
        int node = (b << NBSH) + (t >> 2);
        if (node < N) rowst[node] = st + ex;
    }
    if (b == NBUCK - 1 && t == 0) rowst[N] = E;
    cur[t] = ex;
    __syncthreads();
    for (int e = st + t; e < en; e += 1024) {
        int ent = part[e];
        int src = ent & 0x1FFFF;
        int p = atomicAdd(&cur[((ent >> 17) << 2) | (src >> QSH)], 1);
        csr[st + p] = src;
    }
}

// K7: h1s(bf16, stride 32) = dinv[row] * (x @ W1); W1 in LDS
__global__ void __launch_bounds__(256) gemm1_kernel(const float* __restrict__ x,
                                                    const float* __restrict__ W1,
                                                    const float* __restrict__ dinv,
                                                    unsigned* __restrict__ h1u, int N) {
    __shared__ float w[NFEAT * NHID];
    for (int i = threadIdx.x; i < NFEAT * NHID; i += blockDim.x) w[i] = W1[i];
    __syncthreads();
    int row = blockIdx.x * blockDim.x + threadIdx.x;
    if (row >= N) return;
    float acc[NHID];
#pragma unroll
    for (int j = 0; j < NHID; j++) acc[j] = 0.0f;
    const float4* xr = (const float4*)(x + (size_t)row * NFEAT);
    for (int k4 = 0; k4 < NFEAT / 4; k4++) {
        float4 v = xr[k4];
        const float* wr = &w[k4 * 4 * NHID];
#pragma unroll
        for (int j = 0; j < NHID; j++) acc[j] += v.x * wr[j];
#pragma unroll
        for (int j = 0; j < NHID; j++) acc[j] += v.y * wr[NHID + j];
#pragma unroll
        for (int j = 0; j < NHID; j++) acc[j] += v.z * wr[2 * NHID + j];
#pragma unroll
        for (int j = 0; j < NHID; j++) acc[j] += v.w * wr[3 * NHID + j];
    }
    float di = dinv[row];
    unsigned* o = h1u + (size_t)row * (H1STR / 2);
#pragma unroll
    for (int q = 0; q < NHID / 2; q++)
        o[q] = (unsigned)f2bf(di * acc[2 * q]) | ((unsigned)f2bf(di * acc[2 * q + 1]) << 16);
}

// K8: layer-1 pull aggregation, 12 lanes x 2 feats per node, 16 nodes/192-block.
__global__ void __launch_bounds__(192) agg1_kernel(const int* __restrict__ csr,
                                                   const int* __restrict__ rowst,
                                                   const unsigned* __restrict__ h1u,
                                                   const float* __restrict__ dinv,
                                                   const float* __restrict__ b1,
                                                   float2* __restrict__ hrelu2, int N) {
    int g = threadIdx.x / 12;
    int lane = threadIdx.x - g * 12;
    int node = blockIdx.x * 16 + g;
    if (node >= N) return;
    int st = rowst[node];
    int dg = rowst[node + 1] - st;
    float a0x = 0.f, a0y = 0.f, a1x = 0.f, a1y = 0.f;
    float a2x = 0.f, a2y = 0.f, a3x = 0.f, a3y = 0.f;
    int e = 0;
    for (; e + 4 <= dg; e += 4) {
        int s0 = csr[st + e];
        int s1 = csr[st + e + 1];
        int s2 = csr[st + e + 2];
        int s3 = csr[st + e + 3];
        unsigned u0 = h1u[s0 * (H1STR / 2) + lane];
        unsigned u1 = h1u[s1 * (H1STR / 2) + lane];
        unsigned u2 = h1u[s2 * (H1STR / 2) + lane];
        unsigned u3 = h1u[s3 * (H1STR / 2) + lane];
        a0x += lo_f(u0); a0y += hi_f(u0);
        a1x += lo_f(u1); a1y += hi_f(u1);
        a2x += lo_f(u2); a2y += hi_f(u2);
        a3x += lo_f(u3); a3y += hi_f(u3);
    }
    for (; e < dg; e++) {
        unsigned u = h1u[csr[st + e] * (H1STR / 2) + lane];
        a0x += lo_f(u); a0y += hi_f(u);
    }
    float sx = (a0x + a1x) + (a2x + a3x);
    float sy = (a0y + a1y) + (a2y + a3y);
    unsigned su = h1u[node * (H1STR / 2) + lane];
    float di = dinv[node];
    float v0 = di * (sx + lo_f(su)) + b1[2 * lane];
    float v1 = di * (sy + hi_f(su)) + b1[2 * lane + 1];
    hrelu2[node * 12 + lane] = make_float2(fmaxf(v0, 0.f), fmaxf(v1, 0.f));
}

// K9: h2s(bf16, stride 16) = dinv[row] * (hrelu @ W2)
__global__ void __launch_bounds__(256) fuse2_kernel(const float* __restrict__ hrelu,
                                                    const float* __restrict__ dinv,
                                                    const float* __restrict__ W2,
                                                    unsigned* __restrict__ h2u, int N) {
    __shared__ float w[NHID * NCLS];
    for (int i = threadIdx.x; i < NHID * NCLS; i += blockDim.x) w[i] = W2[i];
    __syncthreads();
    int row = blockIdx.x * blockDim.x + threadIdx.x;
    if (row >= N) return;
    float hr[NHID];
    const float4* h4 = (const float4*)(hrelu + (size_t)row * NHID);
#pragma unroll
    for (int q = 0; q < NHID / 4; q++) {
        float4 hv = h4[q];
        hr[4 * q + 0] = hv.x;
        hr[4 * q + 1] = hv.y;
        hr[4 * q + 2] = hv.z;
        hr[4 * q + 3] = hv.w;
    }
    float acc[NCLS];
#pragma unroll
    for (int j = 0; j < NCLS; j++) acc[j] = 0.0f;
#pragma unroll
    for (int k = 0; k < NHID; k++) {
#pragma unroll
        for (int j = 0; j < NCLS; j++) acc[j] += hr[k] * w[k * NCLS + j];
    }
    float di = dinv[row];
    unsigned* o = h2u + (size_t)row * (NCLS / 2);
#pragma unroll
    for (int q = 0; q < NCLS / 2; q++)
        o[q] = (unsigned)f2bf(di * acc[2 * q]) | ((unsigned)f2bf(di * acc[2 * q + 1]) << 16);
}

// K10: layer-2 pull aggregation, 8 lanes x 2 feats per node + log_softmax
__global__ void __launch_bounds__(256) agg2_kernel(const int* __restrict__ csr,
                                                   const int* __restrict__ rowst,
                                                   const unsigned* __restrict__ h2u,
                                                   const float* __restrict__ dinv,
                                                   const float* __restrict__ b2,
                                                   float2* __restrict__ out2, int N) {
    int g = threadIdx.x >> 3;
    int lane = threadIdx.x & 7;
    int node = blockIdx.x * 32 + g;
    if (node >= N) return;
    int st = rowst[node];
    int dg = rowst[node + 1] - st;
    float a0x = 0.f, a0y = 0.f, a1x = 0.f, a1y = 0.f;
    float a2x = 0.f, a2y = 0.f, a3x = 0.f, a3y = 0.f;
    int e = 0;
    for (; e + 4 <= dg; e += 4) {
        int s0 = csr[st + e];
        int s1 = csr[st + e + 1];
        int s2 = csr[st + e + 2];
        int s3 = csr[st + e + 3];
        unsigned u0 = h2u[s0 * (NCLS / 2) + lane];
        unsigned u1 = h2u[s1 * (NCLS / 2) + lane];
        unsigned u2 = h2u[s2 * (NCLS / 2) + lane];
        unsigned u3 = h2u[s3 * (NCLS / 2) + lane];
        a0x += lo_f(u0); a0y += hi_f(u0);
        a1x += lo_f(u1); a1y += hi_f(u1);
        a2x += lo_f(u2); a2y += hi_f(u2);
        a3x += lo_f(u3); a3y += hi_f(u3);
    }
    for (; e < dg; e++) {
        unsigned u = h2u[csr[st + e] * (NCLS / 2) + lane];
        a0x += lo_f(u); a0y += hi_f(u);
    }
    float sx = (a0x + a1x) + (a2x + a3x);
    float sy = (a0y + a1y) + (a2y + a3y);
    unsigned su = h2u[node * (NCLS / 2) + lane];
    float di = dinv[node];
    float l0 = di * (sx + lo_f(su)) + b2[2 * lane];
    float l1 = di * (sy + hi_f(su)) + b2[2 * lane + 1];
    // log_softmax over 16 feats = pairwise + 8-lane butterfly (groups lane-aligned)
    float m = fmaxf(l0, l1);
#pragma unroll
    for (int o = 1; o < 8; o <<= 1) m = fmaxf(m, __shfl_xor(m, o, 8));
    float ssum = expf(l0 - m) + expf(l1 - m);
#pragma unroll
    for (int o = 1; o < 8; o <<= 1) ssum += __shfl_xor(ssum, o, 8);
    float ls = logf(ssum) + m;
    out2[node * 8 + lane] = make_float2(l0 - ls, l1 - ls);
}

extern "C" void kernel_launch(void* const* d_in, const int* in_sizes, int n_in,
                              void* d_out, int out_size, void* d_ws, size_t ws_size,
                              hipStream_t stream) {
    const float* x  = (const float*)d_in[0];
    const int*   ei = (const int*)d_in[1];
    const float* W1 = (const float*)d_in[2];
    const float* b1 = (const float*)d_in[3];
    const float* W2 = (const float*)d_in[4];
    const float* b2 = (const float*)d_in[5];
    float* out = (float*)d_out;

    const int N = in_sizes[0] / NFEAT;        // 100000
    const int E = in_sizes[1] / 2;            // 3200000
    const int NBUCK = (N + BKN - 1) >> NBSH;  // 391

    // workspace: [deg N][bcnt 512][bbase 513][gcur 512][rowst N+1][csr E] ints,
    // [dinv N] f32, 64B-aligned [h1sb N*32 bf16], 64B-aligned [part E / hrelu 24N] union
    int* deg   = (int*)d_ws;
    int* bcnt  = deg + N;
    int* bbase = bcnt + 512;
    int* gcur  = bbase + 513;
    int* rowst = gcur + 512;
    int* csr   = rowst + (N + 1);
    float* dinv = (float*)(csr + E);
    size_t off = (size_t)(N + 512 + 513 + 512 + (N + 1) + E + N) * 4;
    off = (off + 63) & ~(size_t)63;
    ushort_t* h1sb = (ushort_t*)((char*)d_ws + off);           // 6.4 MB
    ushort_t* h2sb = h1sb;                                     // alias, h1s dead after agg1
    size_t off2 = off + (size_t)N * H1STR * 2;
    off2 = (off2 + 63) & ~(size_t)63;
    int*   part  = (int*)((char*)d_ws + off2);                 // 12.8 MB
    float* hrelu = (float*)part;                               // alias, part dead after csr

    hipMemsetAsync(deg, 0, (size_t)N * sizeof(int), stream);

    deg_kernel<<<(E + 511) / 512, 512, 0, stream>>>(ei, deg, E);
    dinv_kernel<<<(N + 511) / 512, 512, 0, stream>>>(deg, dinv, N);
    bucketsum_kernel<<<NBUCK, 256, 0, stream>>>(deg, bcnt, N);
    bscan_kernel<<<1, 512, 0, stream>>>(bcnt, bbase, gcur, NBUCK, E);
    part1_kernel<<<(E + TILE - 1) / TILE, PT, 0, stream>>>(ei, gcur, part, E);
    csr_kernel<<<NBUCK, 1024, 0, stream>>>(part, bbase, csr, rowst, NBUCK, N, E);
    gemm1_kernel<<<(N + 255) / 256, 256, 0, stream>>>(x, W1, dinv, (unsigned*)h1sb, N);
    agg1_kernel<<<(N + 15) / 16, 192, 0, stream>>>(csr, rowst, (const unsigned*)h1sb,
                                                   dinv, b1, (float2*)hrelu, N);
    fuse2_kernel<<<(N + 255) / 256, 256, 0, stream>>>(hrelu, dinv, W2, (unsigned*)h2sb, N);
    agg2_kernel<<<(N + 31) / 32, 256, 0, stream>>>(csr, rowst, (const unsigned*)h2sb,
                                                   dinv, b2, (float2*)out, N);
}

// Round 8
// 274.480 us; speedup vs baseline: 4.1945x; 1.4314x over previous
//
#include <hip/hip_runtime.h>
#include <math.h>

#define NFEAT 128
#define NHID  24
#define NCLS  16
#define H1STR 32                // h1s bf16 row stride (64 B line-aligned)
#define NBSH  8                 // 256 nodes per bucket
#define BKN   256
#define QSH   15                // src-quarter shift (sub-sort key for L2 phasing)
#define TILE  8192              // edges per partition tile
#define PT    512               // partition block threads

typedef unsigned short ushort_t;

__device__ __forceinline__ float bf2f(ushort_t u) {
    unsigned x = ((unsigned)u) << 16;
    float f; __builtin_memcpy(&f, &x, 4); return f;
}
__device__ __forceinline__ ushort_t f2bf(float f) {
    unsigned x; __builtin_memcpy(&x, &f, 4);
    unsigned r = (x + 0x7FFF + ((x >> 16) & 1)) >> 16;   // RNE
    return (ushort_t)r;
}
__device__ __forceinline__ float lo_f(unsigned u) {   // low bf16 of pair -> float
    unsigned x = u << 16;
    float f; __builtin_memcpy(&f, &x, 4); return f;
}
__device__ __forceinline__ float hi_f(unsigned u) {   // high bf16 of pair -> float
    unsigned x = u & 0xFFFF0000u;
    float f; __builtin_memcpy(&f, &x, 4); return f;
}

// ---------------------------------------------------------------------------
// K1: bucket histogram — LDS counters, one global atomic per (block,bucket).
//     NO per-node global atomics (device-scope atomic RMW write-through is the
//     measured killer: R7 deg_kernel = 128 µs / 100 MB WRITE for 3.2M atomics).
__global__ void __launch_bounds__(512) bhist_kernel(const int* __restrict__ ei,
                                                    int* __restrict__ bhist, int E) {
    __shared__ int lh[512];
    lh[threadIdx.x] = 0;
    __syncthreads();
    int stride = gridDim.x * blockDim.x;
    for (int e = blockIdx.x * blockDim.x + threadIdx.x; e < E; e += stride)
        atomicAdd(&lh[ei[e] >> NBSH], 1);
    __syncthreads();
    if (lh[threadIdx.x]) atomicAdd(&bhist[threadIdx.x], lh[threadIdx.x]);
}

// K2: exclusive scan of bucket counts -> bbase (sentinel), gcur
__global__ void __launch_bounds__(512) bscan_kernel(const int* __restrict__ bcnt,
                                                    int* __restrict__ bbase,
                                                    int* __restrict__ gcur,
                                                    int NBUCK, int E) {
    __shared__ int s[512];
    int t = threadIdx.x;
    int v = (t < NBUCK) ? bcnt[t] : 0;
    s[t] = v;
    __syncthreads();
    for (int o = 1; o < 512; o <<= 1) {
        int x = (t >= o) ? s[t - o] : 0;
        __syncthreads();
        s[t] += x;
        __syncthreads();
    }
    if (t < NBUCK) {
        int ex = s[t] - v;
        bbase[t] = ex;
        gcur[t] = ex;
    }
    if (t == 0) bbase[NBUCK] = E;
}

// K3: LDS-staged partition into 256-node buckets; entry = (local_dst<<17) | src
__global__ void __launch_bounds__(512) part1_kernel(const int* __restrict__ ei,
                                                    int* __restrict__ gcur,
                                                    int* __restrict__ part, int E) {
    __shared__ int stage[TILE];   // 32 KB
    __shared__ int lh[512];       // hist -> cursor
    __shared__ int sc[512];
    __shared__ int lofs[513];
    __shared__ int gbase[512];
    int t = threadIdx.x;
    int e0 = blockIdx.x * TILE;
    int cnt_tile = min(TILE, E - e0);
    lh[t] = 0;
    __syncthreads();
    for (int i = t; i < cnt_tile; i += PT)
        atomicAdd(&lh[ei[e0 + i] >> NBSH], 1);
    __syncthreads();
    sc[t] = lh[t];
    __syncthreads();
    for (int o = 1; o < 512; o <<= 1) {
        int v = (t >= o) ? sc[t - o] : 0;
        __syncthreads();
        sc[t] += v;
        __syncthreads();
    }
    {
        int cb = lh[t];
        int ex = sc[t] - cb;
        lofs[t] = ex;
        gbase[t] = cb ? atomicAdd(&gcur[t], cb) : 0;
        lh[t] = ex;   // LDS cursor
    }
    if (t == 0) lofs[512] = cnt_tile;
    __syncthreads();
    for (int i = t; i < cnt_tile; i += PT) {
        int dst = ei[e0 + i];
        int src = ei[E + e0 + i];
        int b = dst >> NBSH;
        int p = atomicAdd(&lh[b], 1);
        stage[p] = ((dst & (BKN - 1)) << 17) | src;
    }
    __syncthreads();
    for (int i = t; i < cnt_tile; i += PT) {   // coalesced copy-out
        int lo = 0, hi = 511;
        while (lo < hi) {
            int mid = (lo + hi + 1) >> 1;
            if (lofs[mid] <= i) lo = mid; else hi = mid - 1;
        }
        part[gbase[lo] + (i - lofs[lo])] = stage[i];
    }
}

// K4: per-bucket CSR build, key = local_dst*4 + src_quarter (1024 keys).
//     Degree = sum of a node's 4 quarter counts -> dinv computed here (no
//     global-atomic degree pass anywhere).
__global__ void __launch_bounds__(1024) csr_kernel(const int* __restrict__ part,
                                                   const int* __restrict__ bbase,
                                                   int* __restrict__ csr,
                                                   int* __restrict__ rowst,
                                                   float* __restrict__ dinv,
                                                   int NBUCK, int N, int E) {
    __shared__ int h[1024];
    __shared__ int cur[1024];
    int b = blockIdx.x, t = threadIdx.x;
    int st = bbase[b], en = bbase[b + 1];
    h[t] = 0;
    __syncthreads();
    for (int e = st + t; e < en; e += 1024) {
        int ent = part[e];
        atomicAdd(&h[((ent >> 17) << 2) | ((ent & 0x1FFFF) >> QSH)], 1);
    }
    __syncthreads();
    int myc = h[t];
    // per-node degree from quarter counts (reads complete before scan writes:
    // the scan's first write is after its first internal barrier)
    if ((t & 3) == 0) {
        int node = (b << NBSH) + (t >> 2);
        if (node < N)
            dinv[node] = rsqrtf((float)(h[t] + h[t + 1] + h[t + 2] + h[t + 3]) + 1.0f);
    }
    for (int o = 1; o < 1024; o <<= 1) {   // inclusive scan
        int v = (t >= o) ? h[t - o] : 0;
        __syncthreads();
        h[t] += v;
        __syncthreads();
    }
    int ex = h[t] - myc;
    if ((t & 3) == 0) {
        int node = (b << NBSH) + (t >> 2);
        if (node < N) rowst[node] = st + ex;
    }
    if (b == NBUCK - 1 && t == 0) rowst[N] = E;
    cur[t] = ex;
    __syncthreads();
    for (int e = st + t; e < en; e += 1024) {
        int ent = part[e];
        int src = ent & 0x1FFFF;
        int p = atomicAdd(&cur[((ent >> 17) << 2) | (src >> QSH)], 1);
        csr[st + p] = src;
    }
}

// K5: h1s(bf16, stride 32) = dinv[row] * (x @ W1); W1 in LDS
__global__ void __launch_bounds__(256) gemm1_kernel(const float* __restrict__ x,
                                                    const float* __restrict__ W1,
                                                    const float* __restrict__ dinv,
                                                    unsigned* __restrict__ h1u, int N) {
    __shared__ float w[NFEAT * NHID];
    for (int i = threadIdx.x; i < NFEAT * NHID; i += blockDim.x) w[i] = W1[i];
    __syncthreads();
    int row = blockIdx.x * blockDim.x + threadIdx.x;
    if (row >= N) return;
    float acc[NHID];
#pragma unroll
    for (int j = 0; j < NHID; j++) acc[j] = 0.0f;
    const float4* xr = (const float4*)(x + (size_t)row * NFEAT);
    for (int k4 = 0; k4 < NFEAT / 4; k4++) {
        float4 v = xr[k4];
        const float* wr = &w[k4 * 4 * NHID];
#pragma unroll
        for (int j = 0; j < NHID; j++) acc[j] += v.x * wr[j];
#pragma unroll
        for (int j = 0; j < NHID; j++) acc[j] += v.y * wr[NHID + j];
#pragma unroll
        for (int j = 0; j < NHID; j++) acc[j] += v.z * wr[2 * NHID + j];
#pragma unroll
        for (int j = 0; j < NHID; j++) acc[j] += v.w * wr[3 * NHID + j];
    }
    float di = dinv[row];
    unsigned* o = h1u + (size_t)row * (H1STR / 2);
#pragma unroll
    for (int q = 0; q < NHID / 2; q++)
        o[q] = (unsigned)f2bf(di * acc[2 * q]) | ((unsigned)f2bf(di * acc[2 * q + 1]) << 16);
}

// K6: layer-1 pull aggregation, 12 lanes x 2 feats per node, 16 nodes/192-block.
__global__ void __launch_bounds__(192) agg1_kernel(const int* __restrict__ csr,
                                                   const int* __restrict__ rowst,
                                                   const unsigned* __restrict__ h1u,
                                                   const float* __restrict__ dinv,
                                                   const float* __restrict__ b1,
                                                   float2* __restrict__ hrelu2, int N) {
    int g = threadIdx.x / 12;
    int lane = threadIdx.x - g * 12;
    int node = blockIdx.x * 16 + g;
    if (node >= N) return;
    int st = rowst[node];
    int dg = rowst[node + 1] - st;
    float a0x = 0.f, a0y = 0.f, a1x = 0.f, a1y = 0.f;
    float a2x = 0.f, a2y = 0.f, a3x = 0.f, a3y = 0.f;
    int e = 0;
    for (; e + 4 <= dg; e += 4) {
        int s0 = csr[st + e];
        int s1 = csr[st + e + 1];
        int s2 = csr[st + e + 2];
        int s3 = csr[st + e + 3];
        unsigned u0 = h1u[s0 * (H1STR / 2) + lane];
        unsigned u1 = h1u[s1 * (H1STR / 2) + lane];
        unsigned u2 = h1u[s2 * (H1STR / 2) + lane];
        unsigned u3 = h1u[s3 * (H1STR / 2) + lane];
        a0x += lo_f(u0); a0y += hi_f(u0);
        a1x += lo_f(u1); a1y += hi_f(u1);
        a2x += lo_f(u2); a2y += hi_f(u2);
        a3x += lo_f(u3); a3y += hi_f(u3);
    }
    for (; e < dg; e++) {
        unsigned u = h1u[csr[st + e] * (H1STR / 2) + lane];
        a0x += lo_f(u); a0y += hi_f(u);
    }
    float sx = (a0x + a1x) + (a2x + a3x);
    float sy = (a0y + a1y) + (a2y + a3y);
    unsigned su = h1u[node * (H1STR / 2) + lane];
    float di = dinv[node];
    float v0 = di * (sx + lo_f(su)) + b1[2 * lane];
    float v1 = di * (sy + hi_f(su)) + b1[2 * lane + 1];
    hrelu2[node * 12 + lane] = make_float2(fmaxf(v0, 0.f), fmaxf(v1, 0.f));
}

// K7: h2s(bf16, stride 16) = dinv[row] * (hrelu @ W2)
__global__ void __launch_bounds__(256) fuse2_kernel(const float* __restrict__ hrelu,
                                                    const float* __restrict__ dinv,
                                                    const float* __restrict__ W2,
                                                    unsigned* __restrict__ h2u, int N) {
    __shared__ float w[NHID * NCLS];
    for (int i = threadIdx.x; i < NHID * NCLS; i += blockDim.x) w[i] = W2[i];
    __syncthreads();
    int row = blockIdx.x * blockDim.x + threadIdx.x;
    if (row >= N) return;
    float hr[NHID];
    const float4* h4 = (const float4*)(hrelu + (size_t)row * NHID);
#pragma unroll
    for (int q = 0; q < NHID / 4; q++) {
        float4 hv = h4[q];
        hr[4 * q + 0] = hv.x;
        hr[4 * q + 1] = hv.y;
        hr[4 * q + 2] = hv.z;
        hr[4 * q + 3] = hv.w;
    }
    float acc[NCLS];
#pragma unroll
    for (int j = 0; j < NCLS; j++) acc[j] = 0.0f;
#pragma unroll
    for (int k = 0; k < NHID; k++) {
#pragma unroll
        for (int j = 0; j < NCLS; j++) acc[j] += hr[k] * w[k * NCLS + j];
    }
    float di = dinv[row];
    unsigned* o = h2u + (size_t)row * (NCLS / 2);
#pragma unroll
    for (int q = 0; q < NCLS / 2; q++)
        o[q] = (unsigned)f2bf(di * acc[2 * q]) | ((unsigned)f2bf(di * acc[2 * q + 1]) << 16);
}

// K8: layer-2 pull aggregation, 8 lanes x 2 feats per node + log_softmax
__global__ void __launch_bounds__(256) agg2_kernel(const int* __restrict__ csr,
                                                   const int* __restrict__ rowst,
                                                   const unsigned* __restrict__ h2u,
                                                   const float* __restrict__ dinv,
                                                   const float* __restrict__ b2,
                                                   float2* __restrict__ out2, int N) {
    int g = threadIdx.x >> 3;
    int lane = threadIdx.x & 7;
    int node = blockIdx.x * 32 + g;
    if (node >= N) return;
    int st = rowst[node];
    int dg = rowst[node + 1] - st;
    float a0x = 0.f, a0y = 0.f, a1x = 0.f, a1y = 0.f;
    float a2x = 0.f, a2y = 0.f, a3x = 0.f, a3y = 0.f;
    int e = 0;
    for (; e + 4 <= dg; e += 4) {
        int s0 = csr[st + e];
        int s1 = csr[st + e + 1];
        int s2 = csr[st + e + 2];
        int s3 = csr[st + e + 3];
        unsigned u0 = h2u[s0 * (NCLS / 2) + lane];
        unsigned u1 = h2u[s1 * (NCLS / 2) + lane];
        unsigned u2 = h2u[s2 * (NCLS / 2) + lane];
        unsigned u3 = h2u[s3 * (NCLS / 2) + lane];
        a0x += lo_f(u0); a0y += hi_f(u0);
        a1x += lo_f(u1); a1y += hi_f(u1);
        a2x += lo_f(u2); a2y += hi_f(u2);
        a3x += lo_f(u3); a3y += hi_f(u3);
    }
    for (; e < dg; e++) {
        unsigned u = h2u[csr[st + e] * (NCLS / 2) + lane];
        a0x += lo_f(u); a0y += hi_f(u);
    }
    float sx = (a0x + a1x) + (a2x + a3x);
    float sy = (a0y + a1y) + (a2y + a3y);
    unsigned su = h2u[node * (NCLS / 2) + lane];
    float di = dinv[node];
    float l0 = di * (sx + lo_f(su)) + b2[2 * lane];
    float l1 = di * (sy + hi_f(su)) + b2[2 * lane + 1];
    float m = fmaxf(l0, l1);
#pragma unroll
    for (int o = 1; o < 8; o <<= 1) m = fmaxf(m, __shfl_xor(m, o, 8));
    float ssum = expf(l0 - m) + expf(l1 - m);
#pragma unroll
    for (int o = 1; o < 8; o <<= 1) ssum += __shfl_xor(ssum, o, 8);
    float ls = logf(ssum) + m;
    out2[node * 8 + lane] = make_float2(l0 - ls, l1 - ls);
}

extern "C" void kernel_launch(void* const* d_in, const int* in_sizes, int n_in,
                              void* d_out, int out_size, void* d_ws, size_t ws_size,
                              hipStream_t stream) {
    const float* x  = (const float*)d_in[0];
    const int*   ei = (const int*)d_in[1];
    const float* W1 = (const float*)d_in[2];
    const float* b1 = (const float*)d_in[3];
    const float* W2 = (const float*)d_in[4];
    const float* b2 = (const float*)d_in[5];
    float* out = (float*)d_out;

    const int N = in_sizes[0] / NFEAT;        // 100000
    const int E = in_sizes[1] / 2;            // 3200000
    const int NBUCK = (N + BKN - 1) >> NBSH;  // 391

    // workspace: [bhist 512][bbase 513][gcur 512][rowst N+1][csr E] ints,
    // [dinv N] f32, 64B-aligned [h1sb N*32 bf16], 64B-aligned [part E / hrelu 24N]
    int* bhist = (int*)d_ws;
    int* bbase = bhist + 512;
    int* gcur  = bbase + 513;
    int* rowst = gcur + 512;
    int* csr   = rowst + (N + 1);
    float* dinv = (float*)(csr + E);
    size_t off = (size_t)(512 + 513 + 512 + (N + 1) + E + N) * 4;
    off = (off + 63) & ~(size_t)63;
    ushort_t* h1sb = (ushort_t*)((char*)d_ws + off);           // 6.4 MB
    ushort_t* h2sb = h1sb;                                     // alias, h1s dead after agg1
    size_t off2 = off + (size_t)N * H1STR * 2;
    off2 = (off2 + 63) & ~(size_t)63;
    int*   part  = (int*)((char*)d_ws + off2);                 // 12.8 MB
    float* hrelu = (float*)part;                               // alias, part dead after csr

    hipMemsetAsync(bhist, 0, 512 * sizeof(int), stream);

    bhist_kernel<<<512, 512, 0, stream>>>(ei, bhist, E);
    bscan_kernel<<<1, 512, 0, stream>>>(bhist, bbase, gcur, NBUCK, E);
    part1_kernel<<<(E + TILE - 1) / TILE, PT, 0, stream>>>(ei, gcur, part, E);
    csr_kernel<<<NBUCK, 1024, 0, stream>>>(part, bbase, csr, rowst, dinv, NBUCK, N, E);
    gemm1_kernel<<<(N + 255) / 256, 256, 0, stream>>>(x, W1, dinv, (unsigned*)h1sb, N);
    agg1_kernel<<<(N + 15) / 16, 192, 0, stream>>>(csr, rowst, (const unsigned*)h1sb,
                                                   dinv, b1, (float2*)hrelu, N);
    fuse2_kernel<<<(N + 255) / 256, 256, 0, stream>>>(hrelu, dinv, W2, (unsigned*)h2sb, N);
    agg2_kernel<<<(N + 31) / 32, 256, 0, stream>>>(csr, rowst, (const unsigned*)h2sb,
                                                   dinv, b2, (float2*)out, N);
}

// Round 9
// 263.634 us; speedup vs baseline: 4.3671x; 1.0411x over previous
//
#include <hip/hip_runtime.h>
#include <math.h>

#define NFEAT 128
#define NHID  24
#define NCLS  16
#define H1STR 32                // h1s bf16 row stride (64 B line-aligned)
#define NBSH  8                 // 256 nodes per bucket
#define BKN   256
#define QSH   15                // src-quarter shift (sub-sort key for L2 phasing)
#define TILE  4096              // edges per partition tile
#define PT    512               // partition block threads
#define EPT   (TILE / PT)       // 8 edges per thread, constant-indexed

typedef unsigned short ushort_t;

__device__ __forceinline__ float bf2f(ushort_t u) {
    unsigned x = ((unsigned)u) << 16;
    float f; __builtin_memcpy(&f, &x, 4); return f;
}
__device__ __forceinline__ ushort_t f2bf(float f) {
    unsigned x; __builtin_memcpy(&x, &f, 4);
    unsigned r = (x + 0x7FFF + ((x >> 16) & 1)) >> 16;   // RNE
    return (ushort_t)r;
}
__device__ __forceinline__ float lo_f(unsigned u) {
    unsigned x = u << 16;
    float f; __builtin_memcpy(&f, &x, 4); return f;
}
__device__ __forceinline__ float hi_f(unsigned u) {
    unsigned x = u & 0xFFFF0000u;
    float f; __builtin_memcpy(&f, &x, 4); return f;
}

// ---------------------------------------------------------------------------
// K1: bucket histogram — LDS counters, int4 edge loads
__global__ void __launch_bounds__(512) bhist_kernel(const int* __restrict__ ei,
                                                    int* __restrict__ bhist, int E) {
    __shared__ int lh[512];
    lh[threadIdx.x] = 0;
    __syncthreads();
    int stride = gridDim.x * blockDim.x;
    const int4* e4 = (const int4*)ei;
    for (int i = blockIdx.x * blockDim.x + threadIdx.x; i < E / 4; i += stride) {
        int4 v = e4[i];
        atomicAdd(&lh[v.x >> NBSH], 1);
        atomicAdd(&lh[v.y >> NBSH], 1);
        atomicAdd(&lh[v.z >> NBSH], 1);
        atomicAdd(&lh[v.w >> NBSH], 1);
    }
    __syncthreads();
    if (lh[threadIdx.x]) atomicAdd(&bhist[threadIdx.x], lh[threadIdx.x]);
}

// K2: exclusive scan of bucket counts -> bbase (sentinel), gcur
__global__ void __launch_bounds__(512) bscan_kernel(const int* __restrict__ bcnt,
                                                    int* __restrict__ bbase,
                                                    int* __restrict__ gcur,
                                                    int NBUCK, int E) {
    __shared__ int s[512];
    int t = threadIdx.x;
    int v = (t < NBUCK) ? bcnt[t] : 0;
    s[t] = v;
    __syncthreads();
    for (int o = 1; o < 512; o <<= 1) {
        int x = (t >= o) ? s[t - o] : 0;
        __syncthreads();
        s[t] += x;
        __syncthreads();
    }
    if (t < NBUCK) {
        int ex = s[t] - v;
        bbase[t] = ex;
        gcur[t] = ex;
    }
    if (t == 0) bbase[NBUCK] = E;
}

// K3: LDS-staged partition; bucket id recorded per slot (no binary search).
//     Wave-shuffle scan (2 barriers). entry = (local_dst<<17) | src
__global__ void __launch_bounds__(512) part1_kernel(const int* __restrict__ ei,
                                                    int* __restrict__ gcur,
                                                    int* __restrict__ part, int E) {
    __shared__ int stage[TILE];        // 16 KB
    __shared__ ushort_t sbkt[TILE];    // 8 KB
    __shared__ int lh[512];            // hist -> cursor
    __shared__ int lofs[512];
    __shared__ int gbase[512];
    __shared__ int wsum[8];
    int t = threadIdx.x;
    int e0 = blockIdx.x * TILE;
    int cnt = min(TILE, E - e0);
    lh[t] = 0;
    __syncthreads();
    int dstv[EPT];
#pragma unroll
    for (int r = 0; r < EPT; r++) {
        int i = t + r * PT;
        if (i < cnt) {
            int d = ei[e0 + i];
            dstv[r] = d;
            atomicAdd(&lh[d >> NBSH], 1);
        }
    }
    __syncthreads();
    int v = lh[t];
    int s = v;
#pragma unroll
    for (int o = 1; o < 64; o <<= 1) {
        int u = __shfl_up(s, o, 64);
        if ((t & 63) >= o) s += u;
    }
    if ((t & 63) == 63) wsum[t >> 6] = s;
    __syncthreads();
    if (t < 8) {
        int w = wsum[t];
        int ss = w;
#pragma unroll
        for (int o = 1; o < 8; o <<= 1) {
            int u = __shfl_up(ss, o, 8);
            if (t >= o) ss += u;
        }
        wsum[t] = ss - w;   // exclusive
    }
    __syncthreads();
    int ex = s + wsum[t >> 6] - v;
    lofs[t] = ex;
    gbase[t] = v ? atomicAdd(&gcur[t], v) : 0;
    lh[t] = ex;   // cursor
    __syncthreads();
#pragma unroll
    for (int r = 0; r < EPT; r++) {
        int i = t + r * PT;
        if (i < cnt) {
            int dst = dstv[r];
            int src = ei[E + e0 + i];
            int b = dst >> NBSH;
            int p = atomicAdd(&lh[b], 1);
            stage[p] = ((dst & (BKN - 1)) << 17) | src;
            sbkt[p] = (ushort_t)b;
        }
    }
    __syncthreads();
#pragma unroll
    for (int r = 0; r < EPT; r++) {
        int i = t + r * PT;
        if (i < cnt) {
            int b = sbkt[i];
            part[gbase[b] + (i - lofs[b])] = stage[i];
        }
    }
}

// K4: per-bucket CSR build, key = local_dst*4 + src_quarter; wave-shuffle scan.
//     dinv computed from the pre-scan histogram (degree = 4 quarter counts).
__global__ void __launch_bounds__(1024) csr_kernel(const int* __restrict__ part,
                                                   const int* __restrict__ bbase,
                                                   int* __restrict__ csr,
                                                   int* __restrict__ rowst,
                                                   float* __restrict__ dinv,
                                                   int NBUCK, int N, int E) {
    __shared__ int h[1024];
    __shared__ int cur[1024];
    __shared__ int wsum[16];
    int b = blockIdx.x, t = threadIdx.x;
    int st = bbase[b], en = bbase[b + 1];
    h[t] = 0;
    __syncthreads();
    for (int e = st + t; e < en; e += 1024) {
        int ent = part[e];
        atomicAdd(&h[((ent >> 17) << 2) | ((ent & 0x1FFFF) >> QSH)], 1);
    }
    __syncthreads();
    int v = h[t];
    if ((t & 3) == 0) {
        int node = (b << NBSH) + (t >> 2);
        if (node < N)
            dinv[node] = rsqrtf((float)(h[t] + h[t + 1] + h[t + 2] + h[t + 3]) + 1.0f);
    }
    int s = v;
#pragma unroll
    for (int o = 1; o < 64; o <<= 1) {
        int u = __shfl_up(s, o, 64);
        if ((t & 63) >= o) s += u;
    }
    if ((t & 63) == 63) wsum[t >> 6] = s;
    __syncthreads();
    if (t < 16) {
        int w = wsum[t];
        int ss = w;
#pragma unroll
        for (int o = 1; o < 16; o <<= 1) {
            int u = __shfl_up(ss, o, 16);
            if (t >= o) ss += u;
        }
        wsum[t] = ss - w;
    }
    __syncthreads();
    int ex = s + wsum[t >> 6] - v;
    if ((t & 3) == 0) {
        int node = (b << NBSH) + (t >> 2);
        if (node < N) rowst[node] = st + ex;
    }
    if (b == NBUCK - 1 && t == 0) rowst[N] = E;
    cur[t] = ex;
    __syncthreads();
    for (int e = st + t; e < en; e += 1024) {
        int ent = part[e];
        int src = ent & 0x1FFFF;
        int p = atomicAdd(&cur[((ent >> 17) << 2) | (src >> QSH)], 1);
        csr[st + p] = src;
    }
}

// K5: h1s(bf16, stride 32) = dinv[row] * (x @ W1); W1 in LDS, float4 LDS reads
__global__ void __launch_bounds__(256) gemm1_kernel(const float* __restrict__ x,
                                                    const float* __restrict__ W1,
                                                    const float* __restrict__ dinv,
                                                    unsigned* __restrict__ h1u, int N) {
    __shared__ float w[NFEAT * NHID];
    for (int i = threadIdx.x; i < NFEAT * NHID; i += blockDim.x) w[i] = W1[i];
    __syncthreads();
    int row = blockIdx.x * blockDim.x + threadIdx.x;
    if (row >= N) return;
    float acc[NHID];
#pragma unroll
    for (int j = 0; j < NHID; j++) acc[j] = 0.0f;
    const float4* xr = (const float4*)(x + (size_t)row * NFEAT);
    const float4* w4 = (const float4*)w;
    for (int k4 = 0; k4 < NFEAT / 4; k4++) {
        float4 xv = xr[k4];
        float xs[4] = {xv.x, xv.y, xv.z, xv.w};
#pragma unroll
        for (int kk = 0; kk < 4; kk++) {
            float xk = xs[kk];
            const float4* wr = w4 + (size_t)(4 * k4 + kk) * (NHID / 4);
#pragma unroll
            for (int j4 = 0; j4 < NHID / 4; j4++) {
                float4 wv = wr[j4];
                acc[4 * j4 + 0] += xk * wv.x;
                acc[4 * j4 + 1] += xk * wv.y;
                acc[4 * j4 + 2] += xk * wv.z;
                acc[4 * j4 + 3] += xk * wv.w;
            }
        }
    }
    float di = dinv[row];
    unsigned* o = h1u + (size_t)row * (H1STR / 2);
#pragma unroll
    for (int q = 0; q < NHID / 2; q++)
        o[q] = (unsigned)f2bf(di * acc[2 * q]) | ((unsigned)f2bf(di * acc[2 * q + 1]) << 16);
}

// K6: layer-1 pull aggregation + FUSED layer-2 dense transform.
//     Phase A: 12 lanes x 2 feats per node, 16 nodes/192-block -> hrelu in LDS.
//     Phase B: h2u[node] = bf16( dinv * (hrelu @ W2) ), written coalesced.
__global__ void __launch_bounds__(192) agg1_kernel(const int* __restrict__ csr,
                                                   const int* __restrict__ rowst,
                                                   const unsigned* __restrict__ h1u,
                                                   const float* __restrict__ dinv,
                                                   const float* __restrict__ b1,
                                                   const float* __restrict__ W2,
                                                   unsigned* __restrict__ h2u, int N) {
    __shared__ float hl[16][25];          // +1 pad vs 24 to break bank stride
    __shared__ float w2s[NHID * NCLS];    // 384 floats
    int t = threadIdx.x;
    for (int i = t; i < NHID * NCLS; i += 192) w2s[i] = W2[i];
    int g = t / 12;
    int lane = t - g * 12;
    int node = blockIdx.x * 16 + g;
    if (node < N) {
        int st = rowst[node];
        int dg = rowst[node + 1] - st;
        float a0x = 0.f, a0y = 0.f, a1x = 0.f, a1y = 0.f;
        float a2x = 0.f, a2y = 0.f, a3x = 0.f, a3y = 0.f;
        int e = 0;
        for (; e + 4 <= dg; e += 4) {
            int s0 = csr[st + e];
            int s1 = csr[st + e + 1];
            int s2 = csr[st + e + 2];
            int s3 = csr[st + e + 3];
            unsigned u0 = h1u[s0 * (H1STR / 2) + lane];
            unsigned u1 = h1u[s1 * (H1STR / 2) + lane];
            unsigned u2 = h1u[s2 * (H1STR / 2) + lane];
            unsigned u3 = h1u[s3 * (H1STR / 2) + lane];
            a0x += lo_f(u0); a0y += hi_f(u0);
            a1x += lo_f(u1); a1y += hi_f(u1);
            a2x += lo_f(u2); a2y += hi_f(u2);
            a3x += lo_f(u3); a3y += hi_f(u3);
        }
        for (; e < dg; e++) {
            unsigned u = h1u[csr[st + e] * (H1STR / 2) + lane];
            a0x += lo_f(u); a0y += hi_f(u);
        }
        float sx = (a0x + a1x) + (a2x + a3x);
        float sy = (a0y + a1y) + (a2y + a3y);
        unsigned su = h1u[node * (H1STR / 2) + lane];
        float di = dinv[node];
        float v0 = di * (sx + lo_f(su)) + b1[2 * lane];
        float v1 = di * (sy + hi_f(su)) + b1[2 * lane + 1];
        hl[g][2 * lane] = fmaxf(v0, 0.f);
        hl[g][2 * lane + 1] = fmaxf(v1, 0.f);
    }
    __syncthreads();
    if (t < 128) {
        int n2 = t >> 3;
        int op = t & 7;
        int node2 = blockIdx.x * 16 + n2;
        if (node2 < N) {
            float a0 = 0.f, a1 = 0.f;
#pragma unroll
            for (int k = 0; k < NHID; k++) {
                float hv = hl[n2][k];
                a0 += hv * w2s[k * NCLS + 2 * op];
                a1 += hv * w2s[k * NCLS + 2 * op + 1];
            }
            float di2 = dinv[node2];
            h2u[node2 * (NCLS / 2) + op] =
                (unsigned)f2bf(di2 * a0) | ((unsigned)f2bf(di2 * a1) << 16);
        }
    }
}

// K7: layer-2 pull aggregation, 8 lanes x 2 feats per node + log_softmax
__global__ void __launch_bounds__(256) agg2_kernel(const int* __restrict__ csr,
                                                   const int* __restrict__ rowst,
                                                   const unsigned* __restrict__ h2u,
                                                   const float* __restrict__ dinv,
                                                   const float* __restrict__ b2,
                                                   float2* __restrict__ out2, int N) {
    int g = threadIdx.x >> 3;
    int lane = threadIdx.x & 7;
    int node = blockIdx.x * 32 + g;
    if (node >= N) return;
    int st = rowst[node];
    int dg = rowst[node + 1] - st;
    float a0x = 0.f, a0y = 0.f, a1x = 0.f, a1y = 0.f;
    float a2x = 0.f, a2y = 0.f, a3x = 0.f, a3y = 0.f;
    int e = 0;
    for (; e + 4 <= dg; e += 4) {
        int s0 = csr[st + e];
        int s1 = csr[st + e + 1];
        int s2 = csr[st + e + 2];
        int s3 = csr[st + e + 3];
        unsigned u0 = h2u[s0 * (NCLS / 2) + lane];
        unsigned u1 = h2u[s1 * (NCLS / 2) + lane];
        unsigned u2 = h2u[s2 * (NCLS / 2) + lane];
        unsigned u3 = h2u[s3 * (NCLS / 2) + lane];
        a0x += lo_f(u0); a0y += hi_f(u0);
        a1x += lo_f(u1); a1y += hi_f(u1);
        a2x += lo_f(u2); a2y += hi_f(u2);
        a3x += lo_f(u3); a3y += hi_f(u3);
    }
    for (; e < dg; e++) {
        unsigned u = h2u[csr[st + e] * (NCLS / 2) + lane];
        a0x += lo_f(u); a0y += hi_f(u);
    }
    float sx = (a0x + a1x) + (a2x + a3x);
    float sy = (a0y + a1y) + (a2y + a3y);
    unsigned su = h2u[node * (NCLS / 2) + lane];
    float di = dinv[node];
    float l0 = di * (sx + lo_f(su)) + b2[2 * lane];
    float l1 = di * (sy + hi_f(su)) + b2[2 * lane + 1];
    float m = fmaxf(l0, l1);
#pragma unroll
    for (int o = 1; o < 8; o <<= 1) m = fmaxf(m, __shfl_xor(m, o, 8));
    float ssum = expf(l0 - m) + expf(l1 - m);
#pragma unroll
    for (int o = 1; o < 8; o <<= 1) ssum += __shfl_xor(ssum, o, 8);
    float ls = logf(ssum) + m;
    out2[node * 8 + lane] = make_float2(l0 - ls, l1 - ls);
}

extern "C" void kernel_launch(void* const* d_in, const int* in_sizes, int n_in,
                              void* d_out, int out_size, void* d_ws, size_t ws_size,
                              hipStream_t stream) {
    const float* x  = (const float*)d_in[0];
    const int*   ei = (const int*)d_in[1];
    const float* W1 = (const float*)d_in[2];
    const float* b1 = (const float*)d_in[3];
    const float* W2 = (const float*)d_in[4];
    const float* b2 = (const float*)d_in[5];
    float* out = (float*)d_out;

    const int N = in_sizes[0] / NFEAT;        // 100000
    const int E = in_sizes[1] / 2;            // 3200000
    const int NBUCK = (N + BKN - 1) >> NBSH;  // 391

    // workspace: [bhist 512][bbase 513][gcur 512][rowst N+1][csr E] ints,
    // [dinv N] f32, 64B-aligned [h1sb N*32 bf16], 64B-aligned [part E / h2u N*8]
    int* bhist = (int*)d_ws;
    int* bbase = bhist + 512;
    int* gcur  = bbase + 513;
    int* rowst = gcur + 512;
    int* csr   = rowst + (N + 1);
    float* dinv = (float*)(csr + E);
    size_t off = (size_t)(512 + 513 + 512 + (N + 1) + E + N) * 4;
    off = (off + 63) & ~(size_t)63;
    ushort_t* h1sb = (ushort_t*)((char*)d_ws + off);           // 6.4 MB
    size_t off2 = off + (size_t)N * H1STR * 2;
    off2 = (off2 + 63) & ~(size_t)63;
    int* part = (int*)((char*)d_ws + off2);                    // 12.8 MB
    unsigned* h2u = (unsigned*)part;   // alias: part dead after csr_kernel

    hipMemsetAsync(bhist, 0, 512 * sizeof(int), stream);

    bhist_kernel<<<512, 512, 0, stream>>>(ei, bhist, E);
    bscan_kernel<<<1, 512, 0, stream>>>(bhist, bbase, gcur, NBUCK, E);
    part1_kernel<<<(E + TILE - 1) / TILE, PT, 0, stream>>>(ei, gcur, part, E);
    csr_kernel<<<NBUCK, 1024, 0, stream>>>(part, bbase, csr, rowst, dinv, NBUCK, N, E);
    gemm1_kernel<<<(N + 255) / 256, 256, 0, stream>>>(x, W1, dinv, (unsigned*)h1sb, N);
    agg1_kernel<<<(N + 15) / 16, 192, 0, stream>>>(csr, rowst, (const unsigned*)h1sb,
                                                   dinv, b1, W2, h2u, N);
    agg2_kernel<<<(N + 31) / 32, 256, 0, stream>>>(csr, rowst, (const unsigned*)h2u,
                                                   dinv, b2, (float2*)out, N);
}